// Round 4
// baseline (37.361 us; speedup 1.0000x reference)
//
#include <hip/hip_runtime.h>
#include <math.h>

#define UNITS 4096
#define BLK 64        // one wave per row, barrier-free
#define CHUNKS 16     // 64 lanes * 16 chunks * 4 floats = 4096
#define NBINS 1024

__global__ __launch_bounds__(BLK) void srp_kernel(
    const float* __restrict__ pw, const float* __restrict__ bs,
    const float* __restrict__ msk, const float* __restrict__ budget,
    const float* __restrict__ prev, const int* __restrict__ cf,
    float* __restrict__ out) {
  constexpr float TOPK_RATIO = 0.35f;
  constexpr float MIN_BW = 0.1f;
  constexpr float BIAS_W = 0.15f;
  constexpr float TEMP = 0.12f;
  constexpr float EPSF = 1e-6f;
  constexpr float HIV = 1.25f;  // scores <= 1.165 < 1.25
  const float binscale = (float)NBINS / HIV;

  __shared__ int s_h[NBINS];  // 4 KB wave-private histogram

  const int tid = threadIdx.x;  // lane id (wave64)
  const int row = blockIdx.x;
  const size_t base = (size_t)row * UNITS;

  // ---- L = prefix length of ones-mask: 3 dependent ballot rounds, no LDS.
  // Every lane ends up with L (ballot/popc are wave-uniform).
  int L;
  {
    bool t1 = (tid < 8) ? (msk[base + tid * 512 + 511] > 0.0f) : false;
    const int q1 = __popcll(__ballot(t1));  // L in [q1*512, q1*512+512)
    if (q1 == 8) {
      L = 4096;
    } else {
      bool t2 = (tid < 8) ? (msk[base + q1 * 512 + tid * 64 + 63] > 0.0f) : false;
      const int q2 = __popcll(__ballot(t2));
      const int q0 = q1 * 512 + q2 * 64;
      const bool t3 = msk[base + q0 + tid] > 0.0f;
      L = q0 + __popcll(__ballot(t3));
    }
  }

  const float Lf = (float)L;
  float kf = fmaxf(1.0f, rintf(Lf * TOPK_RATIO));  // rintf == jnp.round
  kf = fminf(kf, fmaxf(Lf, 1.0f));
  const int kk = (int)kf;
  const bool no_gate = (kf >= Lf);  // wave-uniform (only L==1 in practice)

  int vf = cf[row];
  vf = min(max(vf, 0), UNITS);
  const int vfL = min(vf, L);  // prefix region [0, vfL): out = prev

  if (!no_gate) {  // zero histogram (wave-uniform branch)
    int4* h4 = reinterpret_cast<int4*>(s_h);
    const int4 z4 = make_int4(0, 0, 0, 0);
    h4[tid] = z4;
    h4[tid + 64] = z4;
    h4[tid + 128] = z4;
    h4[tid + 192] = z4;
  }

  const float4* pw4 = reinterpret_cast<const float4*>(pw + base);
  const float4* bs4 = reinterpret_cast<const float4*>(bs + base);
  const float4* pv4 = reinterpret_cast<const float4*>(prev + base);
  float4* out4 = reinterpret_cast<float4*>(out + base);
  const float4 zero4 = make_float4(0.f, 0.f, 0.f, 0.f);

  // ---- pass 1: scores->regs + histogram; prefix chunks & invalid chunks
  // complete their output stores right here (spreads the 64MB write).
  float4 sc[CHUNKS];
  float prefl = 0.0f;
#pragma unroll
  for (int j = 0; j < CHUNKS; ++j) {
    const int i = tid + j * BLK;
    const int c0 = i * 4;
    float4 s = zero4;
    if (c0 < L) {
      const float4 w = pw4[i];
      const float4 b = bs4[i];
      s.x = fmaxf(w.x, 0.f) + BIAS_W * (MIN_BW + fmaxf(b.x, 0.f));
      s.y = fmaxf(w.y, 0.f) + BIAS_W * (MIN_BW + fmaxf(b.y, 0.f));
      s.z = fmaxf(w.z, 0.f) + BIAS_W * (MIN_BW + fmaxf(b.z, 0.f));
      s.w = fmaxf(w.w, 0.f) + BIAS_W * (MIN_BW + fmaxf(b.w, 0.f));
      if (c0 + 3 < L) {
        if (!no_gate) {
          atomicAdd(&s_h[min(NBINS - 1, (int)(s.x * binscale))], 1);
          atomicAdd(&s_h[min(NBINS - 1, (int)(s.y * binscale))], 1);
          atomicAdd(&s_h[min(NBINS - 1, (int)(s.z * binscale))], 1);
          atomicAdd(&s_h[min(NBINS - 1, (int)(s.w * binscale))], 1);
        }
      } else {  // L-boundary chunk: zero out-of-range components
        if (c0 + 1 >= L) s.y = 0.f;
        if (c0 + 2 >= L) s.z = 0.f;
        if (c0 + 3 >= L) s.w = 0.f;
        if (!no_gate) {
          atomicAdd(&s_h[min(NBINS - 1, (int)(s.x * binscale))], 1);
          if (c0 + 1 < L) atomicAdd(&s_h[min(NBINS - 1, (int)(s.y * binscale))], 1);
          if (c0 + 2 < L) atomicAdd(&s_h[min(NBINS - 1, (int)(s.z * binscale))], 1);
          if (c0 + 3 < L) atomicAdd(&s_h[min(NBINS - 1, (int)(s.w * binscale))], 1);
        }
      }
    } else {
      out4[i] = zero4;  // fully invalid chunk: final value, store now
    }
    sc[j] = s;
    if (c0 < vfL) {
      const float4 t = pv4[i];
      if (c0 + 3 < vfL) {
        prefl += t.x + t.y + t.z + t.w;
        out4[i] = t;  // pure prefix chunk: final value, store now
      } else {        // vfL-boundary: sum masked components; store later
        prefl += t.x + ((c0 + 1 < vfL) ? t.y : 0.f) +
                 ((c0 + 2 < vfL) ? t.z : 0.f) + ((c0 + 3 < vfL) ? t.w : 0.f);
      }
    }
  }

  // ---- 1024-bin select, wave-synchronous (no barriers) ----
  float thr = 0.0f;
  if (!no_gate) {
    const int g = 63 - tid;  // lane owns 16 bins [16g, 16g+16), high bins->low lanes
    const int4 h0 = reinterpret_cast<const int4*>(s_h)[g * 4 + 0];
    const int4 h1 = reinterpret_cast<const int4*>(s_h)[g * 4 + 1];
    const int4 h2 = reinterpret_cast<const int4*>(s_h)[g * 4 + 2];
    const int4 h3 = reinterpret_cast<const int4*>(s_h)[g * 4 + 3];
    const int v = h0.x + h0.y + h0.z + h0.w + h1.x + h1.y + h1.z + h1.w +
                  h2.x + h2.y + h2.z + h2.w + h3.x + h3.y + h3.z + h3.w;
    int x = v;  // inclusive scan over lanes (== suffix sum over bin groups)
#pragma unroll
    for (int o = 1; o < 64; o <<= 1) {
      int y = __shfl_up(x, o, 64);
      if (tid >= o) x += y;
    }
    int binlocal = 0;
    bool found = false;
    if (x >= kk && (x - v) < kk) {  // unique crossing lane
      int cum = x - v;              // count strictly above this group
      const int hh[16] = {h0.x, h0.y, h0.z, h0.w, h1.x, h1.y, h1.z, h1.w,
                          h2.x, h2.y, h2.z, h2.w, h3.x, h3.y, h3.z, h3.w};
      bool f2 = false;
#pragma unroll
      for (int b = 15; b >= 0; --b) {
        cum += hh[b];
        if (!f2 && cum >= kk) { binlocal = g * 16 + b; f2 = true; }
      }
      found = true;
    }
    const unsigned long long m = __ballot(found);
    const int src = __ffsll(m) - 1;
    const int bin = __shfl(binlocal, src, 64);
    // thr err <= HIV/1024 = 1.22e-3; damped by sigmoid(T=0.12)+renormalization
    thr = (float)bin * (HIV / (float)NBINS);
  }

  // ---- gating + tail candidate sum (tail region only), in registers ----
  const float inv_temp = 1.0f / TEMP;
  float tsl = 0.0f;
#pragma unroll
  for (int j = 0; j < CHUNKS; ++j) {
    const int c0 = (tid + j * BLK) * 4;
    if (c0 + 3 >= vfL && c0 < L) {  // intersects tail [vfL, L)
      const float4 s = sc[j];
      float4 sel;
      if (no_gate) {
        sel = s;
      } else {
        sel.x = s.x * __builtin_amdgcn_rcpf(1.0f + __expf((thr - s.x) * inv_temp));
        sel.y = s.y * __builtin_amdgcn_rcpf(1.0f + __expf((thr - s.y) * inv_temp));
        sel.z = s.z * __builtin_amdgcn_rcpf(1.0f + __expf((thr - s.z) * inv_temp));
        sel.w = s.w * __builtin_amdgcn_rcpf(1.0f + __expf((thr - s.w) * inv_temp));
      }
      tsl += ((c0 >= vfL && c0 < L) ? sel.x : 0.f) +
             ((c0 + 1 >= vfL && c0 + 1 < L) ? sel.y : 0.f) +
             ((c0 + 2 >= vfL && c0 + 2 < L) ? sel.z : 0.f) +
             ((c0 + 3 >= vfL && c0 + 3 < L) ? sel.w : 0.f);
      sc[j] = sel;
    }
  }

  // ---- wave butterfly reduce: all lanes get both totals ----
  float prefix_sum = prefl;
  float tail_cand = tsl;
#pragma unroll
  for (int o = 32; o > 0; o >>= 1) {
    prefix_sum += __shfl_xor(prefix_sum, o, 64);
    tail_cand += __shfl_xor(tail_cand, o, 64);
  }

  const int tc = L - vfL;
  const float cand_sum = tail_cand + (tc > 0 ? EPSF : 0.0f);
  const float remaining = fmaxf(budget[row] - prefix_sum, 0.0f);
  const float total = fmaxf(cand_sum, EPSF);
  const float scale = remaining / total;
  const float fb = (tc > 0) ? (EPSF / (float)tc) : 0.0f;

  // ---- write remaining chunks (tail + at most 2 boundary chunks) ----
#pragma unroll
  for (int j = 0; j < CHUNKS; ++j) {
    const int i = tid + j * BLK;
    const int c0 = i * 4;
    if (c0 + 3 < vfL) continue;  // stored in pass 1
    if (c0 >= L) continue;       // zeros stored in pass 1
    const float4 s = sc[j];
    float4 o;
    if (c0 >= vfL && c0 + 3 < L) {  // pure tail chunk
      o.x = (s.x + fb) * scale;
      o.y = (s.y + fb) * scale;
      o.z = (s.z + fb) * scale;
      o.w = (s.w + fb) * scale;
    } else {  // boundary chunk(s): per-component; re-read prev if needed
      const float4 p = (c0 < vfL) ? pv4[i] : zero4;
      o.x = (c0 < vfL) ? p.x : ((c0 < L) ? (s.x + fb) * scale : 0.f);
      o.y = (c0 + 1 < vfL) ? p.y : ((c0 + 1 < L) ? (s.y + fb) * scale : 0.f);
      o.z = (c0 + 2 < vfL) ? p.z : ((c0 + 2 < L) ? (s.z + fb) * scale : 0.f);
      o.w = (c0 + 3 < vfL) ? p.w : ((c0 + 3 < L) ? (s.w + fb) * scale : 0.f);
    }
    out4[i] = o;
  }
}

extern "C" void kernel_launch(void* const* d_in, const int* in_sizes, int n_in,
                              void* d_out, int out_size, void* d_ws, size_t ws_size,
                              hipStream_t stream) {
  const float* pw = (const float*)d_in[0];
  const float* bs = (const float*)d_in[1];
  const float* msk = (const float*)d_in[2];
  const float* bud = (const float*)d_in[3];
  const float* prev = (const float*)d_in[4];
  const int* cf = (const int*)d_in[5];
  float* out = (float*)d_out;
  const int rows = out_size / UNITS;
  srp_kernel<<<dim3(rows), dim3(BLK), 0, stream>>>(pw, bs, msk, bud, prev, cf, out);
}

// Round 5
// 32.141 us; speedup vs baseline: 1.1624x; 1.1624x over previous
//
#include <hip/hip_runtime.h>
#include <math.h>

#define UNITS 4096
#define BLK 256
#define CHUNKS 4      // 256 threads * 4 chunks * 4 floats = 4096
#define NBINS 1024

__global__ __launch_bounds__(BLK) void srp_kernel(
    const float* __restrict__ pw, const float* __restrict__ bs,
    const float* __restrict__ msk, const float* __restrict__ budget,
    const float* __restrict__ prev, const int* __restrict__ cf,
    float* __restrict__ out) {
  constexpr float TOPK_RATIO = 0.35f;
  constexpr float MIN_BW = 0.1f;
  constexpr float BIAS_W = 0.15f;
  constexpr float TEMP = 0.12f;
  constexpr float EPSF = 1e-6f;
  constexpr float HIV = 1.25f;  // scores <= 1.165 < 1.25
  const float binscale = (float)NBINS / HIV;

  __shared__ int s_h[4 * NBINS];  // 16 KB: wave-private histograms
  __shared__ int s_w[4];
  __shared__ int s_bin;
  __shared__ float s_part[8];

  const int tid = threadIdx.x;
  const int lane = tid & 63;
  const int wid = tid >> 6;
  const int row = blockIdx.x;
  const size_t base = (size_t)row * UNITS;

  // ---- wave-private hist zero (wave-local ordering, no barrier needed) ----
  {
    int4* h4 = reinterpret_cast<int4*>(s_h + (wid << 10));
    const int4 z4 = make_int4(0, 0, 0, 0);
    h4[lane] = z4;
    h4[lane + 64] = z4;
    h4[lane + 128] = z4;
    h4[lane + 192] = z4;
  }

  // ---- L = prefix length of ones-mask: each wave computes it redundantly
  // via 3 dependent ballot rounds (no LDS broadcast, no barrier). ----
  int L;
  {
    bool t1 = (lane < 8) ? (msk[base + lane * 512 + 511] > 0.0f) : false;
    const int q1 = __popcll(__ballot(t1));
    if (q1 == 8) {
      L = 4096;
    } else {
      bool t2 = (lane < 8) ? (msk[base + q1 * 512 + lane * 64 + 63] > 0.0f) : false;
      const int q2 = __popcll(__ballot(t2));
      const int q0 = q1 * 512 + q2 * 64;
      const bool t3 = msk[base + q0 + lane] > 0.0f;
      L = q0 + __popcll(__ballot(t3));
    }
  }

  const float Lf = (float)L;
  float kf = fmaxf(1.0f, rintf(Lf * TOPK_RATIO));  // rintf == jnp.round
  kf = fminf(kf, fmaxf(Lf, 1.0f));
  const int kk = (int)kf;
  const bool no_gate = (kf >= Lf);  // block-uniform (same L in all waves)

  int vf = cf[row];
  vf = min(max(vf, 0), UNITS);
  const int vfL = min(vf, L);  // prefix region [0, vfL): out = prev

  const float4* pw4 = reinterpret_cast<const float4*>(pw + base);
  const float4* bs4 = reinterpret_cast<const float4*>(bs + base);
  const float4* pv4 = reinterpret_cast<const float4*>(prev + base);
  float4* out4 = reinterpret_cast<float4*>(out + base);
  const float4 zero4 = make_float4(0.f, 0.f, 0.f, 0.f);
  int* myh = s_h + (wid << 10);

  // ---- pass 1: scores->regs + wave-private histogram; prefix-pure and
  // invalid chunks complete their output stores here (spreads writes). ----
  float4 sc[CHUNKS];
  float prefl = 0.0f;
#pragma unroll
  for (int j = 0; j < CHUNKS; ++j) {
    const int i = tid + j * BLK;
    const int c0 = i * 4;
    float4 s = zero4;
    if (c0 < L) {
      const float4 w = pw4[i];
      const float4 b = bs4[i];
      s.x = fmaxf(w.x, 0.f) + BIAS_W * (MIN_BW + fmaxf(b.x, 0.f));
      s.y = fmaxf(w.y, 0.f) + BIAS_W * (MIN_BW + fmaxf(b.y, 0.f));
      s.z = fmaxf(w.z, 0.f) + BIAS_W * (MIN_BW + fmaxf(b.z, 0.f));
      s.w = fmaxf(w.w, 0.f) + BIAS_W * (MIN_BW + fmaxf(b.w, 0.f));
      if (c0 + 3 < L) {
        if (!no_gate) {
          atomicAdd(&myh[min(NBINS - 1, (int)(s.x * binscale))], 1);
          atomicAdd(&myh[min(NBINS - 1, (int)(s.y * binscale))], 1);
          atomicAdd(&myh[min(NBINS - 1, (int)(s.z * binscale))], 1);
          atomicAdd(&myh[min(NBINS - 1, (int)(s.w * binscale))], 1);
        }
      } else {  // L-boundary chunk
        if (c0 + 1 >= L) s.y = 0.f;
        if (c0 + 2 >= L) s.z = 0.f;
        if (c0 + 3 >= L) s.w = 0.f;
        if (!no_gate) {
          atomicAdd(&myh[min(NBINS - 1, (int)(s.x * binscale))], 1);
          if (c0 + 1 < L) atomicAdd(&myh[min(NBINS - 1, (int)(s.y * binscale))], 1);
          if (c0 + 2 < L) atomicAdd(&myh[min(NBINS - 1, (int)(s.z * binscale))], 1);
          if (c0 + 3 < L) atomicAdd(&myh[min(NBINS - 1, (int)(s.w * binscale))], 1);
        }
      }
    } else {
      out4[i] = zero4;  // final value, store now
    }
    sc[j] = s;
    if (c0 < vfL) {
      const float4 t = pv4[i];
      if (c0 + 3 < vfL) {
        prefl += t.x + t.y + t.z + t.w;
        out4[i] = t;  // final value, store now
      } else {
        prefl += t.x + ((c0 + 1 < vfL) ? t.y : 0.f) +
                 ((c0 + 2 < vfL) ? t.z : 0.f) + ((c0 + 3 < vfL) ? t.w : 0.f);
      }
    }
  }

  // ---- 1024-bin select over merged wave-private hists ----
  float thr = 0.0f;
  if (!no_gate) {
    __syncthreads();  // A: all hist atomics visible
    const int g = 255 - tid;  // thread owns 4 bins [4g, 4g+4), high->low tid
    const int4* H4 = reinterpret_cast<const int4*>(s_h);
    const int4 a0 = H4[g];
    const int4 a1 = H4[256 + g];
    const int4 a2 = H4[512 + g];
    const int4 a3 = H4[768 + g];
    int4 hv;
    hv.x = a0.x + a1.x + a2.x + a3.x;
    hv.y = a0.y + a1.y + a2.y + a3.y;
    hv.z = a0.z + a1.z + a2.z + a3.z;
    hv.w = a0.w + a1.w + a2.w + a3.w;
    const int v = hv.x + hv.y + hv.z + hv.w;
    int x = v;  // inclusive scan over threads (== suffix sum over bins)
#pragma unroll
    for (int o = 1; o < 64; o <<= 1) {
      int y = __shfl_up(x, o, 64);
      if (lane >= o) x += y;
    }
    if (lane == 63) s_w[wid] = x;
    __syncthreads();  // B
    if (wid > 0) x += s_w[0];
    if (wid > 1) x += s_w[1];
    if (wid > 2) x += s_w[2];
    // x = count of elements in bins >= 4g. Unique crossing thread:
    if (x >= kk && (x - v) < kk) {
      int cum = x - v;  // count strictly above this group
      int bin;
      cum += hv.w;
      if (cum >= kk) bin = g * 4 + 3;
      else {
        cum += hv.z;
        if (cum >= kk) bin = g * 4 + 2;
        else {
          cum += hv.y;
          bin = (cum >= kk) ? g * 4 + 1 : g * 4;
        }
      }
      s_bin = bin;
    }
    __syncthreads();  // C
    // thr err <= HIV/1024 = 1.22e-3; damped by sigmoid(T=0.12) + renorm.
    thr = (float)s_bin * (HIV / (float)NBINS);
  }

  // ---- gating + tail candidate sum (tail region only) ----
  const float inv_temp = 1.0f / TEMP;
  float tsl = 0.0f;
#pragma unroll
  for (int j = 0; j < CHUNKS; ++j) {
    const int c0 = (tid + j * BLK) * 4;
    if (c0 + 3 >= vfL && c0 < L) {  // intersects tail [vfL, L)
      const float4 s = sc[j];
      float4 sel;
      if (no_gate) {
        sel = s;
      } else {
        sel.x = s.x * __builtin_amdgcn_rcpf(1.0f + __expf((thr - s.x) * inv_temp));
        sel.y = s.y * __builtin_amdgcn_rcpf(1.0f + __expf((thr - s.y) * inv_temp));
        sel.z = s.z * __builtin_amdgcn_rcpf(1.0f + __expf((thr - s.z) * inv_temp));
        sel.w = s.w * __builtin_amdgcn_rcpf(1.0f + __expf((thr - s.w) * inv_temp));
      }
      tsl += ((c0 >= vfL && c0 < L) ? sel.x : 0.f) +
             ((c0 + 1 >= vfL && c0 + 1 < L) ? sel.y : 0.f) +
             ((c0 + 2 >= vfL && c0 + 2 < L) ? sel.z : 0.f) +
             ((c0 + 3 >= vfL && c0 + 3 < L) ? sel.w : 0.f);
      sc[j] = sel;
    }
  }

  // ---- combined block reduction of (prefix_sum, tail_cand) ----
  {
    float a = prefl;
    float b = tsl;
#pragma unroll
    for (int o = 32; o > 0; o >>= 1) {
      a += __shfl_down(a, o, 64);
      b += __shfl_down(b, o, 64);
    }
    if (lane == 0) {
      s_part[wid] = a;
      s_part[4 + wid] = b;
    }
  }
  __syncthreads();  // D
  const float prefix_sum = s_part[0] + s_part[1] + s_part[2] + s_part[3];
  const float tail_cand = s_part[4] + s_part[5] + s_part[6] + s_part[7];

  const int tc = L - vfL;
  const float cand_sum = tail_cand + (tc > 0 ? EPSF : 0.0f);
  const float remaining = fmaxf(budget[row] - prefix_sum, 0.0f);
  const float total = fmaxf(cand_sum, EPSF);
  const float scale = remaining / total;
  const float fb = (tc > 0) ? (EPSF / (float)tc) : 0.0f;

  // ---- write remaining chunks (tail + at most 2 boundary chunks) ----
#pragma unroll
  for (int j = 0; j < CHUNKS; ++j) {
    const int i = tid + j * BLK;
    const int c0 = i * 4;
    if (c0 + 3 < vfL) continue;  // stored in pass 1
    if (c0 >= L) continue;       // stored in pass 1
    const float4 s = sc[j];
    float4 o;
    if (c0 >= vfL && c0 + 3 < L) {  // pure tail chunk
      o.x = (s.x + fb) * scale;
      o.y = (s.y + fb) * scale;
      o.z = (s.z + fb) * scale;
      o.w = (s.w + fb) * scale;
    } else {  // boundary chunk(s): per-component; re-read prev if needed
      const float4 p = (c0 < vfL) ? pv4[i] : zero4;
      o.x = (c0 < vfL) ? p.x : ((c0 < L) ? (s.x + fb) * scale : 0.f);
      o.y = (c0 + 1 < vfL) ? p.y : ((c0 + 1 < L) ? (s.y + fb) * scale : 0.f);
      o.z = (c0 + 2 < vfL) ? p.z : ((c0 + 2 < L) ? (s.z + fb) * scale : 0.f);
      o.w = (c0 + 3 < vfL) ? p.w : ((c0 + 3 < L) ? (s.w + fb) * scale : 0.f);
    }
    out4[i] = o;
  }
}

extern "C" void kernel_launch(void* const* d_in, const int* in_sizes, int n_in,
                              void* d_out, int out_size, void* d_ws, size_t ws_size,
                              hipStream_t stream) {
  const float* pw = (const float*)d_in[0];
  const float* bs = (const float*)d_in[1];
  const float* msk = (const float*)d_in[2];
  const float* bud = (const float*)d_in[3];
  const float* prev = (const float*)d_in[4];
  const int* cf = (const int*)d_in[5];
  float* out = (float*)d_out;
  const int rows = out_size / UNITS;
  srp_kernel<<<dim3(rows), dim3(BLK), 0, stream>>>(pw, bs, msk, bud, prev, cf, out);
}